// Round 3
// baseline (1690.300 us; speedup 1.0000x reference)
//
#include <hip/hip_runtime.h>

typedef unsigned int uint;
typedef unsigned short ushort;

#define D 128

__device__ __forceinline__ float bf2f(ushort h){ return __uint_as_float(((uint)h)<<16); }
__device__ __forceinline__ ushort f2bf(float f){
  uint u = __float_as_uint(f);
  u += 0x7fff + ((u >> 16) & 1);   // RNE
  return (ushort)(u >> 16);
}
// dtype-agnostic scalar load: bf==1 -> bf16 storage, bf==0 -> fp32 storage
__device__ __forceinline__ float ldf(const void* p, long i, int bf){
  return bf ? bf2f(((const ushort*)p)[i]) : ((const float*)p)[i];
}

// ---------------- dtype detection ----------------
__global__ __launch_bounds__(256) void detect_kernel(const uint* __restrict__ xw,
                                                     int* __restrict__ flag){
  __shared__ int cnt;
  if (threadIdx.x == 0) cnt = 0;
  __syncthreads();
  uint w = xw[threadIdx.x];
  int ef = (int)((w >> 7) & 0xffu);
  if (ef >= 90 && ef <= 142) atomicAdd(&cnt, 1);
  __syncthreads();
  if (threadIdx.x == 0) flag[0] = (cnt >= 128) ? 1 : 0;
}

// ---------------- CSR build (dst is layer-invariant) ----------------
__global__ __launch_bounds__(256) void hist_kernel(const int* __restrict__ dst,
                                                   int* __restrict__ deg, int E_){
  int e = blockIdx.x*256 + threadIdx.x;
  if (e < E_) atomicAdd(&deg[dst[e]], 1);
}

// block scans 512 elements (2/thread); writes block-exclusive prefix + block sum
__global__ __launch_bounds__(256) void scan1_kernel(const int* __restrict__ deg,
                                                    int* __restrict__ rs,
                                                    int* __restrict__ bsum, int Nn){
  __shared__ int s[256];
  int tid = threadIdx.x;
  int base = blockIdx.x*512;
  int i0 = base + 2*tid, i1 = i0 + 1;
  int a = (i0 < Nn) ? deg[i0] : 0;
  int b = (i1 < Nn) ? deg[i1] : 0;
  int p = a + b;
  s[tid] = p; __syncthreads();
  for (int off = 1; off < 256; off <<= 1){
    int t = (tid >= off) ? s[tid-off] : 0;
    __syncthreads();
    s[tid] += t;
    __syncthreads();
  }
  int ex = s[tid] - p;            // exclusive within block
  if (i0 < Nn) rs[i0] = ex;
  if (i1 < Nn) rs[i1] = ex + a;
  if (tid == 255) bsum[blockIdx.x] = s[255];
}

__global__ __launch_bounds__(256) void scan2_kernel(const int* __restrict__ bsum,
                                                    int* __restrict__ boff, int NB){
  __shared__ int s[256];
  int tid = threadIdx.x;
  int v = (tid < NB) ? bsum[tid] : 0;
  s[tid] = v; __syncthreads();
  for (int off = 1; off < 256; off <<= 1){
    int t = (tid >= off) ? s[tid-off] : 0;
    __syncthreads();
    s[tid] += t;
    __syncthreads();
  }
  boff[tid] = s[tid] - v;         // exclusive
}

__global__ __launch_bounds__(256) void scan3_kernel(int* __restrict__ rs,
                                                    const int* __restrict__ boff,
                                                    int* __restrict__ cursor,
                                                    int Nn, int E_){
  int i = blockIdx.x*256 + threadIdx.x;
  if (i < Nn){
    int v = rs[i] + boff[i >> 9];
    rs[i] = v;
    cursor[i] = v;
  }
  if (i == 0) rs[Nn] = E_;
}

__global__ __launch_bounds__(256) void scatter_kernel(const int* __restrict__ dst,
                                                      int* __restrict__ cursor,
                                                      int* __restrict__ perm, int E_){
  int e = blockIdx.x*256 + threadIdx.x;
  if (e < E_){
    int pos = atomicAdd(&cursor[dst[e]], 1);
    perm[pos] = e;
  }
}

// ---------------- edge message + gather-aggregate (no atomics) ----------------
// agg[n] = sum_{e: dst=n} relu(x[src]+vn + attr[e]@W + b)
template<bool FIRST>
__global__ __launch_bounds__(256) void edge_agg_kernel(
    const int* __restrict__ src,
    const int* __restrict__ rs, const int* __restrict__ perm,
    const void* __restrict__ eattr,                 // [E,16]
    const void* __restrict__ ew, const void* __restrict__ eb,
    const void* __restrict__ vn, int layer,
    const void* __restrict__ xin, const float* __restrict__ xws,
    float* __restrict__ agg, int Nn, const int* __restrict__ flag)
{
  int bf = flag[0];
  __shared__ float w[16][D];
  __shared__ float bb[D];
  __shared__ float vv[D];
  int tid = threadIdx.x;
  long wo = (long)layer*16*D;
  for (int i = tid; i < 16*D; i += 256) w[i>>7][i&127] = ldf(ew, wo + i, bf);
  if (tid < D){
    bb[tid] = ldf(eb, (long)layer*D + tid, bf);
    vv[tid] = ldf(vn, (long)layer*D + tid, bf);
  }
  __syncthreads();
  int half = tid >> 7, d = tid & 127;
  for (long n = (long)blockIdx.x*2 + half; n < Nn; n += (long)gridDim.x*2){
    int beg = rs[n], end = rs[n+1];
    float acc = 0.f;
    for (int ii = beg; ii < end; ii++){
      int e = perm[ii];
      int s = src[e];
      float av[16];
      if (bf){
        const uint4* ap = (const uint4*)((const ushort*)eattr + (long)e*16);
        uint4 q0 = ap[0], q1 = ap[1];
        uint uu[8] = {q0.x,q0.y,q0.z,q0.w,q1.x,q1.y,q1.z,q1.w};
        #pragma unroll
        for (int j = 0; j < 8; j++){
          av[2*j]   = __uint_as_float(uu[j] << 16);
          av[2*j+1] = __uint_as_float(uu[j] & 0xffff0000u);
        }
      } else {
        const float4* ap = (const float4*)((const float*)eattr + (long)e*16);
        float4 f0 = ap[0], f1 = ap[1], f2 = ap[2], f3 = ap[3];
        av[0]=f0.x; av[1]=f0.y; av[2]=f0.z; av[3]=f0.w;
        av[4]=f1.x; av[5]=f1.y; av[6]=f1.z; av[7]=f1.w;
        av[8]=f2.x; av[9]=f2.y; av[10]=f2.z; av[11]=f2.w;
        av[12]=f3.x; av[13]=f3.y; av[14]=f3.z; av[15]=f3.w;
      }
      float m = bb[d];
      #pragma unroll
      for (int k = 0; k < 16; k++) m += av[k]*w[k][d];
      float xv = FIRST ? ldf(xin, (long)s*D + d, bf) : xws[(long)s*D + d];
      m += xv + vv[d];
      acc += fmaxf(m, 0.f);
    }
    agg[n*D + d] = acc;
  }
}

// ---------------- node GEMM 128->128, 4x4 register tile ----------------
// PRE:  in = (1+eps)*(x+vn) + agg   else in = x (fp32 ws)
template<bool PRE, bool FIRST, bool RELU>
__global__ __launch_bounds__(256) void mlp_kernel(
    const void* __restrict__ xin, const float* __restrict__ xws,
    const float* __restrict__ agg,
    const void* __restrict__ vn, const void* __restrict__ epsp, int layer,
    const void* __restrict__ W, const void* __restrict__ Bv,
    float* __restrict__ outp, int Nn, const int* __restrict__ flag)
{
  int bf = flag[0];
  __shared__ float w[D][D];        // 64 KB
  __shared__ float hT[D*32];       // 16 KB, hT[k*32 + r]
  __shared__ float bias[D];
  __shared__ float vv[D];
  int tid = threadIdx.x;
  long wo = (long)layer*D*D;
  for (int i = tid; i < D*D; i += 256) w[i>>7][i&127] = ldf(W, wo + i, bf);
  if (tid < D){
    bias[tid] = ldf(Bv, (long)layer*D + tid, bf);
    vv[tid]   = PRE ? ldf(vn, (long)layer*D + tid, bf) : 0.f;
  }
  float epsv = PRE ? (1.f + ldf(epsp, layer, bf)) : 1.f;
  __syncthreads();

  int sr   = tid >> 3;             // staging row 0..31
  int cseg = (tid & 7) << 4;       // staging col base 0..112
  int rgi = tid >> 5, cgi = tid & 31;
  int r0 = rgi*4, c0 = cgi*4;

  for (long base = (long)blockIdx.x*32; base < Nn; base += (long)gridDim.x*32){
    long rg = base + sr;
    if (rg < Nn){
      #pragma unroll
      for (int j = 0; j < 4; j++){
        int c = cseg + j*4;
        float4 hv;
        if (FIRST){
          if (bf){
            ushort4 u = *(const ushort4*)((const ushort*)xin + rg*D + c);
            hv = make_float4(bf2f(u.x),bf2f(u.y),bf2f(u.z),bf2f(u.w));
          } else {
            hv = *(const float4*)((const float*)xin + rg*D + c);
          }
        } else {
          hv = *(const float4*)(xws + rg*D + c);
        }
        if (PRE){
          float4 av = *(const float4*)(agg + rg*D + c);
          hv.x = epsv*(hv.x + vv[c+0]) + av.x;
          hv.y = epsv*(hv.y + vv[c+1]) + av.y;
          hv.z = epsv*(hv.z + vv[c+2]) + av.z;
          hv.w = epsv*(hv.w + vv[c+3]) + av.w;
        }
        hT[(c+0)*32 + sr] = hv.x;
        hT[(c+1)*32 + sr] = hv.y;
        hT[(c+2)*32 + sr] = hv.z;
        hT[(c+3)*32 + sr] = hv.w;
      }
    }
    __syncthreads();
    float acc[4][4];
    #pragma unroll
    for (int ri = 0; ri < 4; ri++)
      #pragma unroll
      for (int ci = 0; ci < 4; ci++) acc[ri][ci] = bias[c0+ci];
    #pragma unroll 4
    for (int k = 0; k < D; k++){
      float4 wv = *(const float4*)&w[k][c0];
      float4 hv = *(const float4*)&hT[k*32 + r0];
      float hr[4] = {hv.x, hv.y, hv.z, hv.w};
      float wc[4] = {wv.x, wv.y, wv.z, wv.w};
      #pragma unroll
      for (int ri = 0; ri < 4; ri++)
        #pragma unroll
        for (int ci = 0; ci < 4; ci++) acc[ri][ci] += hr[ri]*wc[ci];
    }
    #pragma unroll
    for (int ri = 0; ri < 4; ri++){
      long row = base + r0 + ri;
      if (row < Nn){
        float4 o = make_float4(acc[ri][0], acc[ri][1], acc[ri][2], acc[ri][3]);
        if (RELU){
          o.x=fmaxf(o.x,0.f); o.y=fmaxf(o.y,0.f);
          o.z=fmaxf(o.z,0.f); o.w=fmaxf(o.w,0.f);
        }
        *(float4*)(outp + row*D + c0) = o;
      }
    }
    __syncthreads();
  }
}

// ---------------- segment pool (batch is sorted) ----------------
__global__ __launch_bounds__(128) void pool_kernel(
    const float* __restrict__ x, const int* __restrict__ batch,
    int Nn, float* __restrict__ g, int colOff)
{
  int b = blockIdx.x, c = threadIdx.x;
  int lo = 0, hi = Nn;
  while (lo < hi){ int mid = (lo+hi)>>1; if (batch[mid] <  b) lo = mid+1; else hi = mid; }
  int start = lo;
  hi = Nn;
  while (lo < hi){ int mid = (lo+hi)>>1; if (batch[mid] <= b) lo = mid+1; else hi = mid; }
  int end = lo;
  float acc = 0.f;
  for (int r = start; r < end; r++) acc += x[(long)r*D + c];
  g[(long)b*384 + colOff + c] = acc;
}

// ---------------- head: Linear->LN->ReLU x2 -> Linear ----------------
__global__ __launch_bounds__(256) void head_kernel(
    const float* __restrict__ g,
    const void* __restrict__ w1, const void* __restrict__ b1,
    const void* __restrict__ g1, const void* __restrict__ be1,
    const void* __restrict__ w2, const void* __restrict__ b2,
    const void* __restrict__ g2, const void* __restrict__ be2,
    const void* __restrict__ ow, const void* __restrict__ ob,
    void* __restrict__ outp, const int* __restrict__ flag)
{
  int bf = flag[0];
  __shared__ float grow[384];
  __shared__ float h1[256];
  __shared__ float h2[128];
  __shared__ float redA[4], redB[4], stats[2];
  int b = blockIdx.x, tid = threadIdx.x;
  for (int i = tid; i < 384; i += 256) grow[i] = g[(long)b*384 + i];
  __syncthreads();
  float v = ldf(b1, tid, bf);
  for (int k = 0; k < 384; k++) v += grow[k] * ldf(w1, (long)k*256 + tid, bf);
  float s = v, s2 = v*v;
  for (int o = 32; o; o >>= 1){ s += __shfl_down(s,o); s2 += __shfl_down(s2,o); }
  if ((tid & 63) == 0){ redA[tid>>6] = s; redB[tid>>6] = s2; }
  __syncthreads();
  if (tid == 0){
    float S = redA[0]+redA[1]+redA[2]+redA[3];
    float S2 = redB[0]+redB[1]+redB[2]+redB[3];
    float mu = S / 256.f;
    stats[0] = mu; stats[1] = rsqrtf(S2/256.f - mu*mu + 1e-5f);
  }
  __syncthreads();
  float y = (v - stats[0]) * stats[1] * ldf(g1, tid, bf) + ldf(be1, tid, bf);
  h1[tid] = fmaxf(y, 0.f);
  __syncthreads();
  float v2 = 0.f;
  if (tid < 128){
    v2 = ldf(b2, tid, bf);
    for (int k = 0; k < 256; k++) v2 += h1[k] * ldf(w2, (long)k*128 + tid, bf);
  }
  float t = (tid < 128) ? v2 : 0.f;
  s = t; s2 = t*t;
  for (int o = 32; o; o >>= 1){ s += __shfl_down(s,o); s2 += __shfl_down(s2,o); }
  if ((tid & 63) == 0){ redA[tid>>6] = s; redB[tid>>6] = s2; }
  __syncthreads();
  if (tid == 0){
    float S = redA[0]+redA[1]+redA[2]+redA[3];
    float S2 = redB[0]+redB[1]+redB[2]+redB[3];
    float mu = S / 128.f;
    stats[0] = mu; stats[1] = rsqrtf(S2/128.f - mu*mu + 1e-5f);
  }
  __syncthreads();
  if (tid < 128){
    float y2 = (v2 - stats[0]) * stats[1] * ldf(g2, tid, bf) + ldf(be2, tid, bf);
    h2[tid] = fmaxf(y2, 0.f);
  }
  __syncthreads();
  float p = (tid < 128) ? h2[tid] * ldf(ow, tid, bf) : 0.f;
  s = p;
  for (int o = 32; o; o >>= 1) s += __shfl_down(s, o);
  if ((tid & 63) == 0) redA[tid>>6] = s;
  __syncthreads();
  if (tid == 0){
    float r = redA[0]+redA[1]+redA[2]+redA[3] + ldf(ob, 0, bf);
    if (bf) ((ushort*)outp)[b] = f2bf(r);
    else    ((float*)outp)[b]  = r;
  }
}

extern "C" void kernel_launch(void* const* d_in, const int* in_sizes, int n_in,
                              void* d_out, int out_size, void* d_ws, size_t ws_size,
                              hipStream_t stream)
{
  const void* x_in  = d_in[0];
  const int*  eidx  = (const int*)d_in[1];
  const void* eattr = d_in[2];
  const int*  batch = (const int*)d_in[3];
  const void* vn    = d_in[4];
  const void* ew    = d_in[5];
  const void* eb    = d_in[6];
  const void* epsp  = d_in[7];
  const void* w1p   = d_in[8];
  const void* b1p   = d_in[9];
  const void* w2p   = d_in[10];
  const void* b2p   = d_in[11];
  const void* lw1   = d_in[12];
  const void* lb1   = d_in[13];
  const void* ln1g  = d_in[14];
  const void* ln1b  = d_in[15];
  const void* lw2   = d_in[16];
  const void* lb2   = d_in[17];
  const void* ln2g  = d_in[18];
  const void* ln2b  = d_in[19];
  const void* owp   = d_in[20];
  const void* obp   = d_in[21];

  int Nn = in_sizes[0] / D;     // 50000
  int Ee = in_sizes[1] / 2;     // 600000
  int Gg = out_size;            // 512
  const int* srcp = eidx;
  const int* dstp = eidx + Ee;

  // ws layout: A[N*D] f32 (agg / mlp1-out), B[N*D] f32 (x ping-pong),
  // gbuf[G*384], flag, deg[N], rs[N+1], cursor[N], bsum[256], boff[256], perm[E]
  float* A    = (float*)d_ws;
  float* B    = A + (size_t)Nn*D;
  float* gbuf = B + (size_t)Nn*D;
  int*   flag = (int*)(gbuf + (size_t)Gg*384);
  int*   deg    = flag + 1;
  int*   rs     = deg + Nn;           // N+1
  int*   cursor = rs + Nn + 1;
  int*   bsum   = cursor + Nn;
  int*   boff   = bsum + 256;
  int*   perm   = boff + 256;

  detect_kernel<<<1,256,0,stream>>>((const uint*)x_in, flag);

  // CSR build (once; dst invariant across layers)
  int NB = (Nn + 511) / 512;
  hipMemsetAsync(deg, 0, (size_t)Nn*sizeof(int), stream);
  hist_kernel<<<(Ee+255)/256,256,0,stream>>>(dstp, deg, Ee);
  scan1_kernel<<<NB,256,0,stream>>>(deg, rs, bsum, Nn);
  scan2_kernel<<<1,256,0,stream>>>(bsum, boff, NB);
  scan3_kernel<<<(Nn+255)/256,256,0,stream>>>(rs, boff, cursor, Nn, Ee);
  scatter_kernel<<<(Ee+255)/256,256,0,stream>>>(dstp, cursor, perm, Ee);

  int mlpGrid = (Nn + 31) / 32;   // 1563
  for (int i = 0; i < 3; i++){
    if (i == 0)
      edge_agg_kernel<true ><<<4096,256,0,stream>>>(srcp, rs, perm, eattr, ew, eb, vn, i,
                                                    x_in, nullptr, A, Nn, flag);
    else
      edge_agg_kernel<false><<<4096,256,0,stream>>>(srcp, rs, perm, eattr, ew, eb, vn, i,
                                                    nullptr, B, A, Nn, flag);
    // MLP1 (PRE + relu): writes A in-place (rows consumed into LDS before store)
    if (i == 0)
      mlp_kernel<true ,true ,true ><<<mlpGrid,256,0,stream>>>(x_in, nullptr, A, vn, epsp, i,
                                                              w1p, b1p, A, Nn, flag);
    else
      mlp_kernel<true ,false,true ><<<mlpGrid,256,0,stream>>>(nullptr, B, A, vn, epsp, i,
                                                              w1p, b1p, A, Nn, flag);
    // MLP2: A -> B
    mlp_kernel<false,false,false><<<mlpGrid,256,0,stream>>>(nullptr, A, nullptr, vn, epsp, i,
                                                            w2p, b2p, B, Nn, flag);
    pool_kernel<<<Gg,128,0,stream>>>(B, batch, Nn, gbuf, i*D);
  }
  head_kernel<<<Gg,256,0,stream>>>(gbuf, lw1, lb1, ln1g, ln1b,
                                   lw2, lb2, ln2g, ln2b, owp, obp, d_out, flag);
}

// Round 4
// 1280.156 us; speedup vs baseline: 1.3204x; 1.3204x over previous
//
#include <hip/hip_runtime.h>

typedef unsigned int uint;
typedef unsigned short ushort;
typedef __attribute__((ext_vector_type(8))) short short8;
typedef __attribute__((ext_vector_type(4))) float f32x4;

#define D 128

__device__ __forceinline__ float bf2f(ushort h){ return __uint_as_float(((uint)h)<<16); }
__device__ __forceinline__ ushort f2bf(float f){
  uint u = __float_as_uint(f);
  u += 0x7fff + ((u >> 16) & 1);   // RNE
  return (ushort)(u >> 16);
}
// dtype-agnostic scalar load: bf==1 -> bf16 storage, bf==0 -> fp32 storage
__device__ __forceinline__ float ldf(const void* p, long i, int bf){
  return bf ? bf2f(((const ushort*)p)[i]) : ((const float*)p)[i];
}

// ---------------- dtype detection ----------------
__global__ __launch_bounds__(256) void detect_kernel(const uint* __restrict__ xw,
                                                     int* __restrict__ flag){
  __shared__ int cnt;
  if (threadIdx.x == 0) cnt = 0;
  __syncthreads();
  uint w = xw[threadIdx.x];
  int ef = (int)((w >> 7) & 0xffu);
  if (ef >= 90 && ef <= 142) atomicAdd(&cnt, 1);
  __syncthreads();
  if (threadIdx.x == 0) flag[0] = (cnt >= 128) ? 1 : 0;
}

// ---------------- CSR build (dst/src are layer-invariant) ----------------
__global__ __launch_bounds__(256) void hist_kernel(const int* __restrict__ dst,
                                                   int* __restrict__ deg, int E_){
  int e = blockIdx.x*256 + threadIdx.x;
  if (e < E_) atomicAdd(&deg[dst[e]], 1);
}

__global__ __launch_bounds__(256) void scan1_kernel(const int* __restrict__ deg,
                                                    int* __restrict__ rs,
                                                    int* __restrict__ bsum, int Nn){
  __shared__ int s[256];
  int tid = threadIdx.x;
  int base = blockIdx.x*512;
  int i0 = base + 2*tid, i1 = i0 + 1;
  int a = (i0 < Nn) ? deg[i0] : 0;
  int b = (i1 < Nn) ? deg[i1] : 0;
  int p = a + b;
  s[tid] = p; __syncthreads();
  for (int off = 1; off < 256; off <<= 1){
    int t = (tid >= off) ? s[tid-off] : 0;
    __syncthreads();
    s[tid] += t;
    __syncthreads();
  }
  int ex = s[tid] - p;
  if (i0 < Nn) rs[i0] = ex;
  if (i1 < Nn) rs[i1] = ex + a;
  if (tid == 255) bsum[blockIdx.x] = s[255];
}

__global__ __launch_bounds__(256) void scan2_kernel(const int* __restrict__ bsum,
                                                    int* __restrict__ boff, int NB){
  __shared__ int s[256];
  int tid = threadIdx.x;
  int v = (tid < NB) ? bsum[tid] : 0;
  s[tid] = v; __syncthreads();
  for (int off = 1; off < 256; off <<= 1){
    int t = (tid >= off) ? s[tid-off] : 0;
    __syncthreads();
    s[tid] += t;
    __syncthreads();
  }
  boff[tid] = s[tid] - v;
}

__global__ __launch_bounds__(256) void scan3_kernel(int* __restrict__ rs,
                                                    const int* __restrict__ boff,
                                                    int* __restrict__ cursor,
                                                    int Nn, int E_){
  int i = blockIdx.x*256 + threadIdx.x;
  if (i < Nn){
    int v = rs[i] + boff[i >> 9];
    rs[i] = v;
    cursor[i] = v;
  }
  if (i == 0) rs[Nn] = E_;
}

__global__ __launch_bounds__(256) void scatter_kernel(const int* __restrict__ dst,
                                                      int* __restrict__ cursor,
                                                      int* __restrict__ perm, int E_){
  int e = blockIdx.x*256 + threadIdx.x;
  if (e < E_){
    int pos = atomicAdd(&cursor[dst[e]], 1);
    perm[pos] = e;
  }
}

// src_perm[ii] = src[perm[ii]]  (removes one indirection level from edge loop)
__global__ __launch_bounds__(256) void sperm_kernel(const int* __restrict__ perm,
                                                    const int* __restrict__ src,
                                                    int* __restrict__ src_perm, int E_){
  int i = blockIdx.x*256 + threadIdx.x;
  if (i < E_) src_perm[i] = src[perm[i]];
}

// ---------------- W transpose + hi/lo bf16 split (for MFMA B-frags) ----------------
// in: W[l][k][n] (3*128*128, input dtype); out: wT[l][n][k] hi/lo bf16
__global__ __launch_bounds__(256) void trans_kernel(const void* __restrict__ W,
                                                    ushort* __restrict__ hi,
                                                    ushort* __restrict__ lo,
                                                    const int* __restrict__ flag){
  int bf = flag[0];
  int idx = blockIdx.x*256 + threadIdx.x;   // grid covers 3*16384 exactly
  int l = idx >> 14, rem = idx & 16383, k = rem >> 7, n = rem & 127;
  float w = ldf(W, idx, bf);
  ushort h = f2bf(w);
  int di = (l << 14) | (n << 7) | k;
  hi[di] = h;
  lo[di] = f2bf(w - bf2f(h));
}

// ---------------- edge message + gather-aggregate ----------------
// agg[n] = sum_{e: dst=n} relu(x[src]+vn + attr[e]@W + b)
// W column d held in 16 registers per lane; src_perm/perm prefetched.
template<bool FIRST>
__global__ __launch_bounds__(256) void edge_agg_kernel(
    const int* __restrict__ src_perm,
    const int* __restrict__ rs, const int* __restrict__ perm,
    const void* __restrict__ eattr,                 // [E,16]
    const void* __restrict__ ew, const void* __restrict__ eb,
    const void* __restrict__ vn, int layer,
    const void* __restrict__ xin, const float* __restrict__ xws,
    float* __restrict__ agg, int Nn, const int* __restrict__ flag)
{
  int bf = flag[0];
  int tid = threadIdx.x;
  int hh = tid >> 7, d = tid & 127;
  float wreg[16];
  #pragma unroll
  for (int k = 0; k < 16; k++) wreg[k] = ldf(ew, (long)layer*2048 + k*128 + d, bf);
  float bbv = ldf(eb, (long)layer*128 + d, bf);
  float vvv = ldf(vn, (long)layer*128 + d, bf);

  for (long n = (long)blockIdx.x*2 + hh; n < Nn; n += (long)gridDim.x*2){
    int beg = rs[n], end = rs[n+1];
    float acc = 0.f;
    int s_cur = 0, p_cur = 0;
    if (beg < end){ s_cur = src_perm[beg]; p_cur = perm[beg]; }
    for (int ii = beg; ii < end; ii++){
      int s = s_cur, p = p_cur;
      if (ii + 1 < end){ s_cur = src_perm[ii+1]; p_cur = perm[ii+1]; }  // prefetch
      float m = bbv;
      if (bf){
        const uint4* ap = (const uint4*)((const ushort*)eattr + (long)p*16);
        uint4 q0 = ap[0], q1 = ap[1];
        uint uu[8] = {q0.x,q0.y,q0.z,q0.w,q1.x,q1.y,q1.z,q1.w};
        #pragma unroll
        for (int j = 0; j < 8; j++){
          m += __uint_as_float(uu[j] << 16)          * wreg[2*j];
          m += __uint_as_float(uu[j] & 0xffff0000u)  * wreg[2*j+1];
        }
      } else {
        const float4* ap = (const float4*)((const float*)eattr + (long)p*16);
        float4 f0 = ap[0], f1 = ap[1], f2 = ap[2], f3 = ap[3];
        float av[16] = {f0.x,f0.y,f0.z,f0.w, f1.x,f1.y,f1.z,f1.w,
                        f2.x,f2.y,f2.z,f2.w, f3.x,f3.y,f3.z,f3.w};
        #pragma unroll
        for (int k = 0; k < 16; k++) m += av[k]*wreg[k];
      }
      float xv = FIRST ? ldf(xin, (long)s*D + d, bf) : xws[(long)s*D + d];
      m += xv + vvv;
      acc += fmaxf(m, 0.f);
    }
    agg[n*D + d] = acc;
  }
}

// ---------------- node GEMM 128->128 via MFMA (hi/lo split bf16) ----------------
// PRE: h = (1+eps)*(x+vn) + agg  else h = x.  out = h@W + B (+relu)
template<bool PRE, bool FIRST, bool RELU>
__global__ __launch_bounds__(256) void mlp_mfma(
    const void* __restrict__ xin, const float* __restrict__ xws,
    const float* __restrict__ agg,
    const void* __restrict__ vn, const void* __restrict__ epsp, int layer,
    const ushort* __restrict__ wThi, const ushort* __restrict__ wTlo,  // [128][128] this layer
    const void* __restrict__ Bv,
    float* __restrict__ outp, int Nn, const int* __restrict__ flag)
{
  int bf = flag[0];
  __shared__ ushort hHi[64][136];   // +8 pad breaks b128 bank aliasing
  __shared__ ushort hLo[64][136];
  __shared__ float bias[D];
  __shared__ float vvs[D];
  int tid = threadIdx.x;
  if (tid < D){
    bias[tid] = ldf(Bv, (long)layer*D + tid, bf);
    vvs[tid]  = PRE ? ldf(vn, (long)layer*D + tid, bf) : 0.f;
  }
  float epsv = PRE ? (1.f + ldf(epsp, layer, bf)) : 1.f;
  __syncthreads();

  // stage 64 rows -> LDS bf16 hi/lo
  int srow = tid >> 2, scb = (tid & 3) << 5;
  long r = (long)blockIdx.x*64 + srow;
  float hv[32];
  if (r < Nn){
    if (FIRST && bf){
      const ushort* xp = (const ushort*)xin + r*D + scb;
      #pragma unroll
      for (int j = 0; j < 32; j++) hv[j] = bf2f(xp[j]);
    } else {
      const float* xp = (FIRST ? (const float*)xin : xws) + r*D + scb;
      #pragma unroll
      for (int j = 0; j < 32; j++) hv[j] = xp[j];
    }
    if (PRE){
      const float* ap = agg + r*D + scb;
      #pragma unroll
      for (int j = 0; j < 32; j++) hv[j] = epsv*(hv[j] + vvs[scb+j]) + ap[j];
    }
  } else {
    #pragma unroll
    for (int j = 0; j < 32; j++) hv[j] = 0.f;
  }
  #pragma unroll
  for (int j = 0; j < 32; j++){
    ushort hi_ = f2bf(hv[j]);
    hHi[srow][scb+j] = hi_;
    hLo[srow][scb+j] = f2bf(hv[j] - bf2f(hi_));
  }
  __syncthreads();

  // compute: wave wvi handles rows wvi*16..+15
  int lane = tid & 63, wvi = tid >> 6;
  int m = lane & 15, kq = lane >> 4;
  int lr = wvi*16 + m;
  short8 aHi[4], aLo[4];
  #pragma unroll
  for (int ki = 0; ki < 4; ki++){
    aHi[ki] = *(const short8*)&hHi[lr][ki*32 + kq*8];
    aLo[ki] = *(const short8*)&hLo[lr][ki*32 + kq*8];
  }
  long rowBase = (long)blockIdx.x*64 + wvi*16 + kq*4;
  #pragma unroll
  for (int ci = 0; ci < 8; ci++){
    int c = ci*16 + m;                 // D col = lane&15 (+tile), matches B-frag n
    f32x4 acc;
    float bv = bias[c];
    acc[0] = bv; acc[1] = bv; acc[2] = bv; acc[3] = bv;
    const ushort* bp = wThi + ((long)c << 7) + kq*8;
    #pragma unroll
    for (int ki = 0; ki < 4; ki++){
      short8 bfr = *(const short8*)(bp + ki*32);
      acc = __builtin_amdgcn_mfma_f32_16x16x32_bf16(aHi[ki], bfr, acc, 0, 0, 0);
      acc = __builtin_amdgcn_mfma_f32_16x16x32_bf16(aLo[ki], bfr, acc, 0, 0, 0);
    }
    if (!bf){
      const ushort* blp = wTlo + ((long)c << 7) + kq*8;
      #pragma unroll
      for (int ki = 0; ki < 4; ki++){
        short8 blr = *(const short8*)(blp + ki*32);
        acc = __builtin_amdgcn_mfma_f32_16x16x32_bf16(aHi[ki], blr, acc, 0, 0, 0);
      }
    }
    #pragma unroll
    for (int rg = 0; rg < 4; rg++){
      long orow = rowBase + rg;        // C/D: row=(lane>>4)*4+reg (m89-verified)
      if (orow < Nn){
        float o = acc[rg];
        if (RELU) o = fmaxf(o, 0.f);
        outp[orow*D + c] = o;
      }
    }
  }
}

// ---------------- segment pool (batch is sorted) ----------------
__global__ __launch_bounds__(128) void pool_kernel(
    const float* __restrict__ x, const int* __restrict__ batch,
    int Nn, float* __restrict__ g, int colOff)
{
  int b = blockIdx.x, c = threadIdx.x;
  int lo = 0, hi = Nn;
  while (lo < hi){ int mid = (lo+hi)>>1; if (batch[mid] <  b) lo = mid+1; else hi = mid; }
  int start = lo;
  hi = Nn;
  while (lo < hi){ int mid = (lo+hi)>>1; if (batch[mid] <= b) lo = mid+1; else hi = mid; }
  int end = lo;
  float acc = 0.f;
  for (int r = start; r < end; r++) acc += x[(long)r*D + c];
  g[(long)b*384 + colOff + c] = acc;
}

// ---------------- head: Linear->LN->ReLU x2 -> Linear ----------------
__global__ __launch_bounds__(256) void head_kernel(
    const float* __restrict__ g,
    const void* __restrict__ w1, const void* __restrict__ b1,
    const void* __restrict__ g1, const void* __restrict__ be1,
    const void* __restrict__ w2, const void* __restrict__ b2,
    const void* __restrict__ g2, const void* __restrict__ be2,
    const void* __restrict__ ow, const void* __restrict__ ob,
    void* __restrict__ outp, const int* __restrict__ flag)
{
  int bf = flag[0];
  __shared__ float grow[384];
  __shared__ float h1[256];
  __shared__ float h2[128];
  __shared__ float redA[4], redB[4], stats[2];
  int b = blockIdx.x, tid = threadIdx.x;
  for (int i = tid; i < 384; i += 256) grow[i] = g[(long)b*384 + i];
  __syncthreads();
  float v = ldf(b1, tid, bf);
  for (int k = 0; k < 384; k++) v += grow[k] * ldf(w1, (long)k*256 + tid, bf);
  float s = v, s2 = v*v;
  for (int o = 32; o; o >>= 1){ s += __shfl_down(s,o); s2 += __shfl_down(s2,o); }
  if ((tid & 63) == 0){ redA[tid>>6] = s; redB[tid>>6] = s2; }
  __syncthreads();
  if (tid == 0){
    float S = redA[0]+redA[1]+redA[2]+redA[3];
    float S2 = redB[0]+redB[1]+redB[2]+redB[3];
    float mu = S / 256.f;
    stats[0] = mu; stats[1] = rsqrtf(S2/256.f - mu*mu + 1e-5f);
  }
  __syncthreads();
  float y = (v - stats[0]) * stats[1] * ldf(g1, tid, bf) + ldf(be1, tid, bf);
  h1[tid] = fmaxf(y, 0.f);
  __syncthreads();
  float v2 = 0.f;
  if (tid < 128){
    v2 = ldf(b2, tid, bf);
    for (int k = 0; k < 256; k++) v2 += h1[k] * ldf(w2, (long)k*128 + tid, bf);
  }
  float t = (tid < 128) ? v2 : 0.f;
  s = t; s2 = t*t;
  for (int o = 32; o; o >>= 1){ s += __shfl_down(s,o); s2 += __shfl_down(s2,o); }
  if ((tid & 63) == 0){ redA[tid>>6] = s; redB[tid>>6] = s2; }
  __syncthreads();
  if (tid == 0){
    float S = redA[0]+redA[1]+redA[2]+redA[3];
    float S2 = redB[0]+redB[1]+redB[2]+redB[3];
    float mu = S / 128.f;
    stats[0] = mu; stats[1] = rsqrtf(S2/128.f - mu*mu + 1e-5f);
  }
  __syncthreads();
  if (tid < 128){
    float y2 = (v2 - stats[0]) * stats[1] * ldf(g2, tid, bf) + ldf(be2, tid, bf);
    h2[tid] = fmaxf(y2, 0.f);
  }
  __syncthreads();
  float p = (tid < 128) ? h2[tid] * ldf(ow, tid, bf) : 0.f;
  s = p;
  for (int o = 32; o; o >>= 1) s += __shfl_down(s, o);
  if ((tid & 63) == 0) redA[tid>>6] = s;
  __syncthreads();
  if (tid == 0){
    float r = redA[0]+redA[1]+redA[2]+redA[3] + ldf(ob, 0, bf);
    if (bf) ((ushort*)outp)[b] = f2bf(r);
    else    ((float*)outp)[b]  = r;
  }
}

extern "C" void kernel_launch(void* const* d_in, const int* in_sizes, int n_in,
                              void* d_out, int out_size, void* d_ws, size_t ws_size,
                              hipStream_t stream)
{
  const void* x_in  = d_in[0];
  const int*  eidx  = (const int*)d_in[1];
  const void* eattr = d_in[2];
  const int*  batch = (const int*)d_in[3];
  const void* vn    = d_in[4];
  const void* ew    = d_in[5];
  const void* eb    = d_in[6];
  const void* epsp  = d_in[7];
  const void* w1p   = d_in[8];
  const void* b1p   = d_in[9];
  const void* w2p   = d_in[10];
  const void* b2p   = d_in[11];
  const void* lw1   = d_in[12];
  const void* lb1   = d_in[13];
  const void* ln1g  = d_in[14];
  const void* ln1b  = d_in[15];
  const void* lw2   = d_in[16];
  const void* lb2   = d_in[17];
  const void* ln2g  = d_in[18];
  const void* ln2b  = d_in[19];
  const void* owp   = d_in[20];
  const void* obp   = d_in[21];

  int Nn = in_sizes[0] / D;     // 50000
  int Ee = in_sizes[1] / 2;     // 600000
  int Gg = out_size;            // 512
  const int* srcp = eidx;
  const int* dstp = eidx + Ee;

  // ws layout: A[N*D] f32, B[N*D] f32, gbuf[G*384] f32,
  //            wT1hi/wT1lo/wT2hi/wT2lo [3*128*128] ushort each,
  //            flag, deg[N], rs[N+1], cursor[N], bsum[256], boff[256],
  //            perm[E], src_perm[E]
  float*  A     = (float*)d_ws;
  float*  B     = A + (size_t)Nn*D;
  float*  gbuf  = B + (size_t)Nn*D;
  ushort* wT1hi = (ushort*)(gbuf + (size_t)Gg*384);
  ushort* wT1lo = wT1hi + 3*D*D;
  ushort* wT2hi = wT1lo + 3*D*D;
  ushort* wT2lo = wT2hi + 3*D*D;
  int*    flag  = (int*)(wT2lo + 3*D*D);
  int*    deg     = flag + 1;
  int*    rs      = deg + Nn;        // N+1
  int*    cursor  = rs + Nn + 1;
  int*    bsum    = cursor + Nn;
  int*    boff    = bsum + 256;
  int*    perm    = boff + 256;
  int*    src_perm= perm + Ee;

  detect_kernel<<<1,256,0,stream>>>((const uint*)x_in, flag);

  // CSR build (once; dst/src invariant across layers)
  int NB = (Nn + 511) / 512;
  hipMemsetAsync(deg, 0, (size_t)Nn*sizeof(int), stream);
  hist_kernel<<<(Ee+255)/256,256,0,stream>>>(dstp, deg, Ee);
  scan1_kernel<<<NB,256,0,stream>>>(deg, rs, bsum, Nn);
  scan2_kernel<<<1,256,0,stream>>>(bsum, boff, NB);
  scan3_kernel<<<(Nn+255)/256,256,0,stream>>>(rs, boff, cursor, Nn, Ee);
  scatter_kernel<<<(Ee+255)/256,256,0,stream>>>(dstp, cursor, perm, Ee);
  sperm_kernel<<<(Ee+255)/256,256,0,stream>>>(perm, srcp, src_perm, Ee);

  // W transpose + hi/lo split (3*128*128 each, grid exact)
  trans_kernel<<<192,256,0,stream>>>(w1p, wT1hi, wT1lo, flag);
  trans_kernel<<<192,256,0,stream>>>(w2p, wT2hi, wT2lo, flag);

  int mlpGrid = (Nn + 63) / 64;   // 782
  for (int i = 0; i < 3; i++){
    if (i == 0)
      edge_agg_kernel<true ><<<4096,256,0,stream>>>(src_perm, rs, perm, eattr, ew, eb, vn, i,
                                                    x_in, nullptr, A, Nn, flag);
    else
      edge_agg_kernel<false><<<4096,256,0,stream>>>(src_perm, rs, perm, eattr, ew, eb, vn, i,
                                                    nullptr, B, A, Nn, flag);
    // MLP1 (PRE + relu): in-place A -> A (rows staged to LDS before stores)
    if (i == 0)
      mlp_mfma<true ,true ,true ><<<mlpGrid,256,0,stream>>>(x_in, nullptr, A, vn, epsp, i,
                                                            wT1hi + (size_t)i*D*D, wT1lo + (size_t)i*D*D,
                                                            b1p, A, Nn, flag);
    else
      mlp_mfma<true ,false,true ><<<mlpGrid,256,0,stream>>>(nullptr, B, A, vn, epsp, i,
                                                            wT1hi + (size_t)i*D*D, wT1lo + (size_t)i*D*D,
                                                            b1p, A, Nn, flag);
    // MLP2: A -> B
    mlp_mfma<false,false,false><<<mlpGrid,256,0,stream>>>(nullptr, A, nullptr, vn, epsp, i,
                                                          wT2hi + (size_t)i*D*D, wT2lo + (size_t)i*D*D,
                                                          b2p, B, Nn, flag);
    pool_kernel<<<Gg,128,0,stream>>>(B, batch, Nn, gbuf, i*D);
  }
  head_kernel<<<Gg,256,0,stream>>>(gbuf, lw1, lb1, ln1g, ln1b,
                                   lw2, lb2, ln2g, ln2b, owp, obp, d_out, flag);
}

// Round 5
// 1077.659 us; speedup vs baseline: 1.5685x; 1.1879x over previous
//
#include <hip/hip_runtime.h>

typedef unsigned int uint;
typedef unsigned short ushort;
typedef __attribute__((ext_vector_type(8))) short short8;
typedef __attribute__((ext_vector_type(4))) float f32x4;
typedef __attribute__((ext_vector_type(2))) float f32x2;

#define D 128

__device__ __forceinline__ float bf2f(ushort h){ return __uint_as_float(((uint)h)<<16); }
__device__ __forceinline__ ushort f2bf(float f){
  uint u = __float_as_uint(f);
  u += 0x7fff + ((u >> 16) & 1);   // RNE
  return (ushort)(u >> 16);
}
__device__ __forceinline__ float ldf(const void* p, long i, int bf){
  return bf ? bf2f(((const ushort*)p)[i]) : ((const float*)p)[i];
}
__device__ __forceinline__ int imin(int a, int b){ return a < b ? a : b; }

// ---------------- dtype detection ----------------
__global__ __launch_bounds__(256) void detect_kernel(const uint* __restrict__ xw,
                                                     int* __restrict__ flag){
  __shared__ int cnt;
  if (threadIdx.x == 0) cnt = 0;
  __syncthreads();
  uint w = xw[threadIdx.x];
  int ef = (int)((w >> 7) & 0xffu);
  if (ef >= 90 && ef <= 142) atomicAdd(&cnt, 1);
  __syncthreads();
  if (threadIdx.x == 0) flag[0] = (cnt >= 128) ? 1 : 0;
}

// ---------------- CSR build (dst/src are layer-invariant) ----------------
__global__ __launch_bounds__(256) void hist_kernel(const int* __restrict__ dst,
                                                   int* __restrict__ deg, int E_){
  int e = blockIdx.x*256 + threadIdx.x;
  if (e < E_) atomicAdd(&deg[dst[e]], 1);
}

__global__ __launch_bounds__(256) void scan1_kernel(const int* __restrict__ deg,
                                                    int* __restrict__ rs,
                                                    int* __restrict__ bsum, int Nn){
  __shared__ int s[256];
  int tid = threadIdx.x;
  int base = blockIdx.x*512;
  int i0 = base + 2*tid, i1 = i0 + 1;
  int a = (i0 < Nn) ? deg[i0] : 0;
  int b = (i1 < Nn) ? deg[i1] : 0;
  int p = a + b;
  s[tid] = p; __syncthreads();
  for (int off = 1; off < 256; off <<= 1){
    int t = (tid >= off) ? s[tid-off] : 0;
    __syncthreads();
    s[tid] += t;
    __syncthreads();
  }
  int ex = s[tid] - p;
  if (i0 < Nn) rs[i0] = ex;
  if (i1 < Nn) rs[i1] = ex + a;
  if (tid == 255) bsum[blockIdx.x] = s[255];
}

__global__ __launch_bounds__(256) void scan2_kernel(const int* __restrict__ bsum,
                                                    int* __restrict__ boff, int NB){
  __shared__ int s[256];
  int tid = threadIdx.x;
  int v = (tid < NB) ? bsum[tid] : 0;
  s[tid] = v; __syncthreads();
  for (int off = 1; off < 256; off <<= 1){
    int t = (tid >= off) ? s[tid-off] : 0;
    __syncthreads();
    s[tid] += t;
    __syncthreads();
  }
  boff[tid] = s[tid] - v;
}

__global__ __launch_bounds__(256) void scan3_kernel(int* __restrict__ rs,
                                                    const int* __restrict__ boff,
                                                    int* __restrict__ cursor,
                                                    int Nn, int E_){
  int i = blockIdx.x*256 + threadIdx.x;
  if (i < Nn){
    int v = rs[i] + boff[i >> 9];
    rs[i] = v;
    cursor[i] = v;
  }
  if (i == 0) rs[Nn] = E_;
}

// writes (src[e], e) pairs grouped by dst
__global__ __launch_bounds__(256) void scatter_kernel(const int* __restrict__ dst,
                                                      const int* __restrict__ src,
                                                      int* __restrict__ cursor,
                                                      int2* __restrict__ spp, int E_){
  int e = blockIdx.x*256 + threadIdx.x;
  if (e < E_){
    int pos = atomicAdd(&cursor[dst[e]], 1);
    spp[pos] = make_int2(src[e], e);
  }
}

// ---------------- W transpose + hi/lo bf16 split ----------------
__global__ __launch_bounds__(256) void trans_kernel(const void* __restrict__ W,
                                                    ushort* __restrict__ hi,
                                                    ushort* __restrict__ lo,
                                                    const int* __restrict__ flag){
  int bf = flag[0];
  int idx = blockIdx.x*256 + threadIdx.x;   // grid covers 3*16384 exactly
  int l = idx >> 14, rem = idx & 16383, k = rem >> 7, n = rem & 127;
  float w = ldf(W, idx, bf);
  ushort h = f2bf(w);
  int di = (l << 14) | (n << 7) | k;
  hi[di] = h;
  lo[di] = f2bf(w - bf2f(h));
}

// ---------------- edge gather-aggregate + PRE combine ----------------
// hpre[n] = (1+eps)*(x[n]+vn) + sum_{e:dst=n} relu(x[src]+vn + attr@W + b)
// one wave per node; lane covers dims {2*lane, 2*lane+1}; 4 edges in flight
template<bool FIRST>
__global__ __launch_bounds__(256) void edge_agg_kernel(
    const int2* __restrict__ spp, const int* __restrict__ rs,
    const void* __restrict__ eattr,
    const void* __restrict__ ew, const void* __restrict__ eb,
    const void* __restrict__ vn, const void* __restrict__ epsp, int layer,
    const void* __restrict__ xin, const float* __restrict__ xws,
    float* __restrict__ hpre, int Nn, const int* __restrict__ flag)
{
  int bf = flag[0];
  int lane = threadIdx.x & 63, wvi = threadIdx.x >> 6;
  int d0 = lane << 1;
  f32x2 w2[16];
  #pragma unroll
  for (int k = 0; k < 16; k++){
    w2[k][0] = ldf(ew, (long)layer*2048 + k*128 + d0,     bf);
    w2[k][1] = ldf(ew, (long)layer*2048 + k*128 + d0 + 1, bf);
  }
  f32x2 vn2, cv;
  vn2[0] = ldf(vn, (long)layer*128 + d0,     bf);
  vn2[1] = ldf(vn, (long)layer*128 + d0 + 1, bf);
  cv[0] = ldf(eb, (long)layer*128 + d0,     bf) + vn2[0];
  cv[1] = ldf(eb, (long)layer*128 + d0 + 1, bf) + vn2[1];
  float epsv = 1.f + ldf(epsp, layer, bf);

  for (int n = blockIdx.x*4 + wvi; n < Nn; n += gridDim.x*4){
    int beg = rs[n], end = rs[n+1];
    f32x2 acc = {0.f, 0.f};
    for (int ii = beg; ii < end; ii += 4){
      int2 ip = spp[imin(ii + (lane & 3), end - 1)];
      int ss[4], pp[4];
      #pragma unroll
      for (int j = 0; j < 4; j++){ ss[j] = __shfl(ip.x, j); pp[j] = __shfl(ip.y, j); }
      // issue all 4 x-row gathers first (independent, in flight together)
      f32x2 xv[4];
      #pragma unroll
      for (int j = 0; j < 4; j++){
        if (FIRST && bf){
          uint u = *(const uint*)((const ushort*)xin + (long)ss[j]*D + d0);
          xv[j][0] = __uint_as_float(u << 16);
          xv[j][1] = __uint_as_float(u & 0xffff0000u);
        } else {
          const float* xp = FIRST ? (const float*)xin : xws;
          xv[j] = *(const f32x2*)(xp + (long)ss[j]*D + d0);
        }
      }
      #pragma unroll
      for (int j = 0; j < 4; j++){
        f32x2 m = cv + xv[j];
        if (bf){
          const uint4* ap = (const uint4*)((const ushort*)eattr + (long)pp[j]*16);
          uint4 q0 = ap[0], q1 = ap[1];
          uint uu[8] = {q0.x,q0.y,q0.z,q0.w,q1.x,q1.y,q1.z,q1.w};
          #pragma unroll
          for (int t = 0; t < 8; t++){
            float a0 = __uint_as_float(uu[t] << 16);
            float a1 = __uint_as_float(uu[t] & 0xffff0000u);
            m[0] += a0*w2[2*t][0];   m[1] += a0*w2[2*t][1];
            m[0] += a1*w2[2*t+1][0]; m[1] += a1*w2[2*t+1][1];
          }
        } else {
          const float4* ap = (const float4*)((const float*)eattr + (long)pp[j]*16);
          float4 f0 = ap[0], f1 = ap[1], f2 = ap[2], f3 = ap[3];
          float av[16] = {f0.x,f0.y,f0.z,f0.w, f1.x,f1.y,f1.z,f1.w,
                          f2.x,f2.y,f2.z,f2.w, f3.x,f3.y,f3.z,f3.w};
          #pragma unroll
          for (int k = 0; k < 16; k++){ m[0] += av[k]*w2[k][0]; m[1] += av[k]*w2[k][1]; }
        }
        if (ii + j < end){            // wave-uniform
          acc[0] += fmaxf(m[0], 0.f);
          acc[1] += fmaxf(m[1], 0.f);
        }
      }
    }
    // own-row PRE combine
    f32x2 xn;
    if (FIRST && bf){
      uint u = *(const uint*)((const ushort*)xin + (long)n*D + d0);
      xn[0] = __uint_as_float(u << 16);
      xn[1] = __uint_as_float(u & 0xffff0000u);
    } else {
      const float* xp = FIRST ? (const float*)xin : xws;
      xn = *(const f32x2*)(xp + (long)n*D + d0);
    }
    f32x2 hp;
    hp[0] = epsv*(xn[0] + vn2[0]) + acc[0];
    hp[1] = epsv*(xn[1] + vn2[1]) + acc[1];
    *(f32x2*)(hpre + (long)n*D + d0) = hp;
  }
}

// ---------------- fused node MLP: out = relu(h@W1+b1)@W2+b2 (MFMA hi/lo) ----------------
__global__ __launch_bounds__(256) void mlp_fused(
    const float* __restrict__ hpre,
    const ushort* __restrict__ w1hi, const ushort* __restrict__ w1lo,
    const ushort* __restrict__ w2hi, const ushort* __restrict__ w2lo,
    const void* __restrict__ b1v, const void* __restrict__ b2v, int layer,
    float* __restrict__ outp, int Nn, const int* __restrict__ flag)
{
  int bf = flag[0];
  __shared__ ushort hHi[64][136];   // +8 pad
  __shared__ ushort hLo[64][136];
  __shared__ float bias1[D], bias2[D];
  int tid = threadIdx.x;
  if (tid < D){
    bias1[tid] = ldf(b1v, (long)layer*D + tid, bf);
    bias2[tid] = ldf(b2v, (long)layer*D + tid, bf);
  }
  // stage 64 rows of hpre -> LDS hi/lo
  int srow = tid >> 2, scb = (tid & 3) << 5;
  long r = (long)blockIdx.x*64 + srow;
  {
    float hv[32];
    if (r < Nn){
      const float* xp = hpre + r*D + scb;
      #pragma unroll
      for (int j = 0; j < 32; j++) hv[j] = xp[j];
    } else {
      #pragma unroll
      for (int j = 0; j < 32; j++) hv[j] = 0.f;
    }
    #pragma unroll
    for (int j = 0; j < 32; j++){
      ushort hi_ = f2bf(hv[j]);
      hHi[srow][scb+j] = hi_;
      hLo[srow][scb+j] = f2bf(hv[j] - bf2f(hi_));
    }
  }
  __syncthreads();

  int lane = tid & 63, wvi = tid >> 6;
  int m = lane & 15, kq = lane >> 4;
  int lr = wvi*16 + m;
  short8 aHi[4], aLo[4];
  #pragma unroll
  for (int ki = 0; ki < 4; ki++){
    aHi[ki] = *(const short8*)&hHi[lr][ki*32 + kq*8];
    aLo[ki] = *(const short8*)&hLo[lr][ki*32 + kq*8];
  }
  // GEMM1 -> h1 (C layout), relu
  float h1[8][4];
  #pragma unroll
  for (int ci = 0; ci < 8; ci++){
    int c = ci*16 + m;
    f32x4 acc;
    float bv = bias1[c];
    acc[0] = bv; acc[1] = bv; acc[2] = bv; acc[3] = bv;
    const ushort* bp = w1hi + ((long)c << 7) + kq*8;
    #pragma unroll
    for (int ki = 0; ki < 4; ki++){
      short8 bfr = *(const short8*)(bp + ki*32);
      acc = __builtin_amdgcn_mfma_f32_16x16x32_bf16(aHi[ki], bfr, acc, 0, 0, 0);
      acc = __builtin_amdgcn_mfma_f32_16x16x32_bf16(aLo[ki], bfr, acc, 0, 0, 0);
    }
    if (!bf){
      const ushort* blp = w1lo + ((long)c << 7) + kq*8;
      #pragma unroll
      for (int ki = 0; ki < 4; ki++){
        short8 blr = *(const short8*)(blp + ki*32);
        acc = __builtin_amdgcn_mfma_f32_16x16x32_bf16(aHi[ki], blr, acc, 0, 0, 0);
      }
    }
    #pragma unroll
    for (int rg = 0; rg < 4; rg++) h1[ci][rg] = fmaxf(acc[rg], 0.f);
  }
  __syncthreads();   // all frag reads done; safe to overwrite LDS
  // write h1 back (C layout scatter), hi/lo split
  #pragma unroll
  for (int ci = 0; ci < 8; ci++){
    int c = ci*16 + m;
    #pragma unroll
    for (int rg = 0; rg < 4; rg++){
      int rl = wvi*16 + kq*4 + rg;
      float v = h1[ci][rg];
      ushort hi_ = f2bf(v);
      hHi[rl][c] = hi_;
      hLo[rl][c] = f2bf(v - bf2f(hi_));
    }
  }
  __syncthreads();
  // reload A-frags for GEMM2
  #pragma unroll
  for (int ki = 0; ki < 4; ki++){
    aHi[ki] = *(const short8*)&hHi[lr][ki*32 + kq*8];
    aLo[ki] = *(const short8*)&hLo[lr][ki*32 + kq*8];
  }
  long rowBase = (long)blockIdx.x*64 + wvi*16 + kq*4;
  #pragma unroll
  for (int ci = 0; ci < 8; ci++){
    int c = ci*16 + m;
    f32x4 acc;
    float bv = bias2[c];
    acc[0] = bv; acc[1] = bv; acc[2] = bv; acc[3] = bv;
    const ushort* bp = w2hi + ((long)c << 7) + kq*8;
    #pragma unroll
    for (int ki = 0; ki < 4; ki++){
      short8 bfr = *(const short8*)(bp + ki*32);
      acc = __builtin_amdgcn_mfma_f32_16x16x32_bf16(aHi[ki], bfr, acc, 0, 0, 0);
      acc = __builtin_amdgcn_mfma_f32_16x16x32_bf16(aLo[ki], bfr, acc, 0, 0, 0);
    }
    // h1 is a true fp32 intermediate -> always need lo-A; fp32-W also needs lo-B
    if (!bf){
      const ushort* blp = w2lo + ((long)c << 7) + kq*8;
      #pragma unroll
      for (int ki = 0; ki < 4; ki++){
        short8 blr = *(const short8*)(blp + ki*32);
        acc = __builtin_amdgcn_mfma_f32_16x16x32_bf16(aHi[ki], blr, acc, 0, 0, 0);
      }
    }
    #pragma unroll
    for (int rg = 0; rg < 4; rg++){
      long orow = rowBase + rg;
      if (orow < Nn) outp[orow*D + c] = acc[rg];
    }
  }
}

// ---------------- segment pool (batch is sorted) ----------------
__global__ __launch_bounds__(128) void pool_kernel(
    const float* __restrict__ x, const int* __restrict__ batch,
    int Nn, float* __restrict__ g, int colOff)
{
  int b = blockIdx.x, c = threadIdx.x;
  int lo = 0, hi = Nn;
  while (lo < hi){ int mid = (lo+hi)>>1; if (batch[mid] <  b) lo = mid+1; else hi = mid; }
  int start = lo;
  hi = Nn;
  while (lo < hi){ int mid = (lo+hi)>>1; if (batch[mid] <= b) lo = mid+1; else hi = mid; }
  int end = lo;
  float acc = 0.f;
  for (int r = start; r < end; r++) acc += x[(long)r*D + c];
  g[(long)b*384 + colOff + c] = acc;
}

// ---------------- head: Linear->LN->ReLU x2 -> Linear ----------------
__global__ __launch_bounds__(256) void head_kernel(
    const float* __restrict__ g,
    const void* __restrict__ w1, const void* __restrict__ b1,
    const void* __restrict__ g1, const void* __restrict__ be1,
    const void* __restrict__ w2, const void* __restrict__ b2,
    const void* __restrict__ g2, const void* __restrict__ be2,
    const void* __restrict__ ow, const void* __restrict__ ob,
    void* __restrict__ outp, const int* __restrict__ flag)
{
  int bf = flag[0];
  __shared__ float grow[384];
  __shared__ float h1[256];
  __shared__ float h2[128];
  __shared__ float redA[4], redB[4], stats[2];
  int b = blockIdx.x, tid = threadIdx.x;
  for (int i = tid; i < 384; i += 256) grow[i] = g[(long)b*384 + i];
  __syncthreads();
  float v = ldf(b1, tid, bf);
  for (int k = 0; k < 384; k++) v += grow[k] * ldf(w1, (long)k*256 + tid, bf);
  float s = v, s2 = v*v;
  for (int o = 32; o; o >>= 1){ s += __shfl_down(s,o); s2 += __shfl_down(s2,o); }
  if ((tid & 63) == 0){ redA[tid>>6] = s; redB[tid>>6] = s2; }
  __syncthreads();
  if (tid == 0){
    float S = redA[0]+redA[1]+redA[2]+redA[3];
    float S2 = redB[0]+redB[1]+redB[2]+redB[3];
    float mu = S / 256.f;
    stats[0] = mu; stats[1] = rsqrtf(S2/256.f - mu*mu + 1e-5f);
  }
  __syncthreads();
  float y = (v - stats[0]) * stats[1] * ldf(g1, tid, bf) + ldf(be1, tid, bf);
  h1[tid] = fmaxf(y, 0.f);
  __syncthreads();
  float v2 = 0.f;
  if (tid < 128){
    v2 = ldf(b2, tid, bf);
    for (int k = 0; k < 256; k++) v2 += h1[k] * ldf(w2, (long)k*128 + tid, bf);
  }
  float t = (tid < 128) ? v2 : 0.f;
  s = t; s2 = t*t;
  for (int o = 32; o; o >>= 1){ s += __shfl_down(s,o); s2 += __shfl_down(s2,o); }
  if ((tid & 63) == 0){ redA[tid>>6] = s; redB[tid>>6] = s2; }
  __syncthreads();
  if (tid == 0){
    float S = redA[0]+redA[1]+redA[2]+redA[3];
    float S2 = redB[0]+redB[1]+redB[2]+redB[3];
    float mu = S / 128.f;
    stats[0] = mu; stats[1] = rsqrtf(S2/128.f - mu*mu + 1e-5f);
  }
  __syncthreads();
  if (tid < 128){
    float y2 = (v2 - stats[0]) * stats[1] * ldf(g2, tid, bf) + ldf(be2, tid, bf);
    h2[tid] = fmaxf(y2, 0.f);
  }
  __syncthreads();
  float p = (tid < 128) ? h2[tid] * ldf(ow, tid, bf) : 0.f;
  s = p;
  for (int o = 32; o; o >>= 1) s += __shfl_down(s, o);
  if ((tid & 63) == 0) redA[tid>>6] = s;
  __syncthreads();
  if (tid == 0){
    float r = redA[0]+redA[1]+redA[2]+redA[3] + ldf(ob, 0, bf);
    if (bf) ((ushort*)outp)[b] = f2bf(r);
    else    ((float*)outp)[b]  = r;
  }
}

extern "C" void kernel_launch(void* const* d_in, const int* in_sizes, int n_in,
                              void* d_out, int out_size, void* d_ws, size_t ws_size,
                              hipStream_t stream)
{
  const void* x_in  = d_in[0];
  const int*  eidx  = (const int*)d_in[1];
  const void* eattr = d_in[2];
  const int*  batch = (const int*)d_in[3];
  const void* vn    = d_in[4];
  const void* ew    = d_in[5];
  const void* eb    = d_in[6];
  const void* epsp  = d_in[7];
  const void* w1p   = d_in[8];
  const void* b1p   = d_in[9];
  const void* w2p   = d_in[10];
  const void* b2p   = d_in[11];
  const void* lw1   = d_in[12];
  const void* lb1   = d_in[13];
  const void* ln1g  = d_in[14];
  const void* ln1b  = d_in[15];
  const void* lw2   = d_in[16];
  const void* lb2   = d_in[17];
  const void* ln2g  = d_in[18];
  const void* ln2b  = d_in[19];
  const void* owp   = d_in[20];
  const void* obp   = d_in[21];

  int Nn = in_sizes[0] / D;     // 50000
  int Ee = in_sizes[1] / 2;     // 600000
  int Gg = out_size;            // 512
  const int* srcp = eidx;
  const int* dstp = eidx + Ee;

  // ws: A/B/C [N*D] f32, gbuf, wT splits, flag, CSR arrays, spp int2[E]
  float*  A     = (float*)d_ws;                 // hpre scratch
  float*  B     = A + (size_t)Nn*D;             // layer outs (ping)
  float*  C     = B + (size_t)Nn*D;             // layer outs (pong)
  float*  gbuf  = C + (size_t)Nn*D;
  ushort* wT1hi = (ushort*)(gbuf + (size_t)Gg*384);
  ushort* wT1lo = wT1hi + 3*D*D;
  ushort* wT2hi = wT1lo + 3*D*D;
  ushort* wT2lo = wT2hi + 3*D*D;
  int*    flag  = (int*)(wT2lo + 3*D*D);
  int*    deg     = flag + 1;
  int*    rs      = deg + Nn;        // N+1
  int*    cursor  = rs + Nn + 1;
  int*    bsum    = cursor + Nn;
  int*    boff    = bsum + 256;
  int2*   spp     = (int2*)(boff + 256);

  detect_kernel<<<1,256,0,stream>>>((const uint*)x_in, flag);

  // CSR build (once; dst/src invariant across layers)
  int NB = (Nn + 511) / 512;
  hipMemsetAsync(deg, 0, (size_t)Nn*sizeof(int), stream);
  hist_kernel<<<(Ee+255)/256,256,0,stream>>>(dstp, deg, Ee);
  scan1_kernel<<<NB,256,0,stream>>>(deg, rs, bsum, Nn);
  scan2_kernel<<<1,256,0,stream>>>(bsum, boff, NB);
  scan3_kernel<<<(Nn+255)/256,256,0,stream>>>(rs, boff, cursor, Nn, Ee);
  scatter_kernel<<<(Ee+255)/256,256,0,stream>>>(dstp, srcp, cursor, spp, Ee);

  trans_kernel<<<192,256,0,stream>>>(w1p, wT1hi, wT1lo, flag);
  trans_kernel<<<192,256,0,stream>>>(w2p, wT2hi, wT2lo, flag);

  int mlpGrid = (Nn + 63) / 64;   // 782
  float* xcur = nullptr;          // fp32 layer input (layers 1,2)
  for (int i = 0; i < 3; i++){
    float* out = (i == 1) ? C : B;    // L0->B, L1->C, L2->B
    if (i == 0)
      edge_agg_kernel<true ><<<2048,256,0,stream>>>(spp, rs, eattr, ew, eb, vn, epsp, i,
                                                    x_in, nullptr, A, Nn, flag);
    else
      edge_agg_kernel<false><<<2048,256,0,stream>>>(spp, rs, eattr, ew, eb, vn, epsp, i,
                                                    nullptr, xcur, A, Nn, flag);
    mlp_fused<<<mlpGrid,256,0,stream>>>(A,
                                        wT1hi + (size_t)i*D*D, wT1lo + (size_t)i*D*D,
                                        wT2hi + (size_t)i*D*D, wT2lo + (size_t)i*D*D,
                                        b1p, b2p, i, out, Nn, flag);
    pool_kernel<<<Gg,128,0,stream>>>(out, batch, Nn, gbuf, i*D);
    xcur = out;
  }
  head_kernel<<<Gg,256,0,stream>>>(gbuf, lw1, lb1, ln1g, ln1b,
                                   lw2, lb2, ln2g, ln2b, owp, obp, d_out, flag);
}

// Round 6
// 823.055 us; speedup vs baseline: 2.0537x; 1.3093x over previous
//
#include <hip/hip_runtime.h>

typedef unsigned int uint;
typedef unsigned short ushort;
typedef __attribute__((ext_vector_type(8))) short short8;
typedef __attribute__((ext_vector_type(4))) float f32x4;
typedef __attribute__((ext_vector_type(2))) float f32x2;

#define D 128

__device__ __forceinline__ float bf2f(ushort h){ return __uint_as_float(((uint)h)<<16); }
__device__ __forceinline__ ushort f2bf(float f){
  uint u = __float_as_uint(f);
  u += 0x7fff + ((u >> 16) & 1);   // RNE
  return (ushort)(u >> 16);
}
__device__ __forceinline__ float ldf(const void* p, long i, int bf){
  return bf ? bf2f(((const ushort*)p)[i]) : ((const float*)p)[i];
}
__device__ __forceinline__ int imin(int a, int b){ return a < b ? a : b; }

// ---------------- dtype detection ----------------
__global__ __launch_bounds__(256) void detect_kernel(const uint* __restrict__ xw,
                                                     int* __restrict__ flag){
  __shared__ int cnt;
  if (threadIdx.x == 0) cnt = 0;
  __syncthreads();
  uint w = xw[threadIdx.x];
  int ef = (int)((w >> 7) & 0xffu);
  if (ef >= 90 && ef <= 142) atomicAdd(&cnt, 1);
  __syncthreads();
  if (threadIdx.x == 0) flag[0] = (cnt >= 128) ? 1 : 0;
}

// ---------------- CSR build (dst/src are layer-invariant) ----------------
__global__ __launch_bounds__(256) void hist_kernel(const int* __restrict__ dst,
                                                   int* __restrict__ deg, int E_){
  int e = blockIdx.x*256 + threadIdx.x;
  if (e < E_) atomicAdd(&deg[dst[e]], 1);
}

__global__ __launch_bounds__(256) void scan1_kernel(const int* __restrict__ deg,
                                                    int* __restrict__ rs,
                                                    int* __restrict__ bsum, int Nn){
  __shared__ int s[256];
  int tid = threadIdx.x;
  int base = blockIdx.x*512;
  int i0 = base + 2*tid, i1 = i0 + 1;
  int a = (i0 < Nn) ? deg[i0] : 0;
  int b = (i1 < Nn) ? deg[i1] : 0;
  int p = a + b;
  s[tid] = p; __syncthreads();
  for (int off = 1; off < 256; off <<= 1){
    int t = (tid >= off) ? s[tid-off] : 0;
    __syncthreads();
    s[tid] += t;
    __syncthreads();
  }
  int ex = s[tid] - p;
  if (i0 < Nn) rs[i0] = ex;
  if (i1 < Nn) rs[i1] = ex + a;
  if (tid == 255) bsum[blockIdx.x] = s[255];
}

__global__ __launch_bounds__(256) void scan2_kernel(const int* __restrict__ bsum,
                                                    int* __restrict__ boff, int NB){
  __shared__ int s[256];
  int tid = threadIdx.x;
  int v = (tid < NB) ? bsum[tid] : 0;
  s[tid] = v; __syncthreads();
  for (int off = 1; off < 256; off <<= 1){
    int t = (tid >= off) ? s[tid-off] : 0;
    __syncthreads();
    s[tid] += t;
    __syncthreads();
  }
  boff[tid] = s[tid] - v;
}

__global__ __launch_bounds__(256) void scan3_kernel(int* __restrict__ rs,
                                                    const int* __restrict__ boff,
                                                    int* __restrict__ cursor,
                                                    int Nn, int E_){
  int i = blockIdx.x*256 + threadIdx.x;
  if (i < Nn){
    int v = rs[i] + boff[i >> 9];
    rs[i] = v;
    cursor[i] = v;
  }
  if (i == 0) rs[Nn] = E_;
}

__global__ __launch_bounds__(256) void scatter_kernel(const int* __restrict__ dst,
                                                      const int* __restrict__ src,
                                                      int* __restrict__ cursor,
                                                      int2* __restrict__ spp, int E_){
  int e = blockIdx.x*256 + threadIdx.x;
  if (e < E_){
    int pos = atomicAdd(&cursor[dst[e]], 1);
    spp[pos] = make_int2(src[e], e);
  }
}

// ---------------- W transpose + hi/lo bf16 split ----------------
__global__ __launch_bounds__(256) void trans_kernel(const void* __restrict__ W,
                                                    ushort* __restrict__ hi,
                                                    ushort* __restrict__ lo,
                                                    const int* __restrict__ flag){
  int bf = flag[0];
  int idx = blockIdx.x*256 + threadIdx.x;   // grid covers 3*16384 exactly
  int l = idx >> 14, rem = idx & 16383, k = rem >> 7, n = rem & 127;
  float w = ldf(W, idx, bf);
  ushort h = f2bf(w);
  int di = (l << 14) | (n << 7) | k;
  hi[di] = h;
  lo[di] = f2bf(w - bf2f(h));
}

// ---------------- edge gather-aggregate + PRE combine ----------------
// hpre[n] = (1+eps)*(x[n]+vn) + sum_{e:dst=n} relu(x[src]+vn + attr@W + b)
// one wave per 2 consecutive nodes (contiguous perm range), 8-edge chunks;
// attr staged via LDS wave-scratch -> broadcast b128 reads.
template<bool FIRST>
__global__ __launch_bounds__(256) void edge_agg_kernel(
    const int2* __restrict__ spp, const int* __restrict__ rs,
    const void* __restrict__ eattr,
    const void* __restrict__ ew, const void* __restrict__ eb,
    const void* __restrict__ vn, const void* __restrict__ epsp, int layer,
    const void* __restrict__ xin, const float* __restrict__ xws,
    float* __restrict__ hpre, int Nn, const int* __restrict__ flag)
{
  int bf = flag[0];
  __shared__ float ascr[4][8][16];           // per-wave attr scratch (2 KB)
  int lane = threadIdx.x & 63, wvi = threadIdx.x >> 6;
  int d0 = lane << 1;
  int je = lane >> 3;        // edge slot this lane stages attr for
  int ke = lane & 7;         // attr pair index
  f32x2 w2[16];
  #pragma unroll
  for (int k = 0; k < 16; k++){
    w2[k][0] = ldf(ew, (long)layer*2048 + k*128 + d0,     bf);
    w2[k][1] = ldf(ew, (long)layer*2048 + k*128 + d0 + 1, bf);
  }
  f32x2 vn2, cv;
  vn2[0] = ldf(vn, (long)layer*128 + d0,     bf);
  vn2[1] = ldf(vn, (long)layer*128 + d0 + 1, bf);
  cv[0] = ldf(eb, (long)layer*128 + d0,     bf) + vn2[0];
  cv[1] = ldf(eb, (long)layer*128 + d0 + 1, bf) + vn2[1];
  float epsv = 1.f + ldf(epsp, layer, bf);
  const float* xp32 = FIRST ? (const float*)xin : xws;

  for (int n0 = (blockIdx.x*4 + wvi)*2; n0 < Nn; n0 += gridDim.x*8){
    int beg   = rs[n0];
    int split = rs[n0+1];
    int end   = (n0+2 <= Nn) ? rs[n0+2] : split;
    f32x2 accA = {0.f, 0.f}, accB = {0.f, 0.f};
    for (int ii = beg; ii < end; ii += 8){
      int2 ip = spp[imin(ii + ke, end - 1)];     // lane&7 -> edge slot
      int pe = __shfl(ip.y, je);                 // attr row for slot je
      f32x2 a2;
      if (bf){
        uint u = *(const uint*)((const ushort*)eattr + (long)pe*16 + ke*2);
        a2[0] = __uint_as_float(u << 16);
        a2[1] = __uint_as_float(u & 0xffff0000u);
      } else {
        a2 = *(const f32x2*)((const float*)eattr + (long)pe*16 + ke*2);
      }
      *(f32x2*)&ascr[wvi][je][ke*2] = a2;
      int ss[8];
      #pragma unroll
      for (int j = 0; j < 8; j++) ss[j] = __shfl(ip.x, j);
      f32x2 xv[8];
      #pragma unroll
      for (int j = 0; j < 8; j++){
        if (FIRST && bf){
          uint u = *(const uint*)((const ushort*)xin + (long)ss[j]*D + d0);
          xv[j][0] = __uint_as_float(u << 16);
          xv[j][1] = __uint_as_float(u & 0xffff0000u);
        } else {
          xv[j] = *(const f32x2*)(xp32 + (long)ss[j]*D + d0);
        }
      }
      #pragma unroll
      for (int j = 0; j < 8; j++){
        float m0 = cv[0] + xv[j][0], m1 = cv[1] + xv[j][1];
        #pragma unroll
        for (int t = 0; t < 4; t++){
          float4 q = *(const float4*)&ascr[wvi][j][t*4];   // broadcast read
          m0 += q.x*w2[4*t][0] + q.y*w2[4*t+1][0] + q.z*w2[4*t+2][0] + q.w*w2[4*t+3][0];
          m1 += q.x*w2[4*t][1] + q.y*w2[4*t+1][1] + q.z*w2[4*t+2][1] + q.w*w2[4*t+3][1];
        }
        int gidx = ii + j;
        float r0 = fmaxf(m0, 0.f), r1 = fmaxf(m1, 0.f);
        bool inA = gidx < split;
        bool inB = (!inA) && (gidx < end);
        accA[0] += inA ? r0 : 0.f;  accA[1] += inA ? r1 : 0.f;
        accB[0] += inB ? r0 : 0.f;  accB[1] += inB ? r1 : 0.f;
      }
    }
    // PRE combine + store both rows
    f32x2 xn;
    if (FIRST && bf){
      uint u = *(const uint*)((const ushort*)xin + (long)n0*D + d0);
      xn[0] = __uint_as_float(u << 16);
      xn[1] = __uint_as_float(u & 0xffff0000u);
    } else {
      xn = *(const f32x2*)(xp32 + (long)n0*D + d0);
    }
    f32x2 hp;
    hp[0] = epsv*(xn[0] + vn2[0]) + accA[0];
    hp[1] = epsv*(xn[1] + vn2[1]) + accA[1];
    *(f32x2*)(hpre + (long)n0*D + d0) = hp;
    if (n0 + 1 < Nn){
      f32x2 xm;
      if (FIRST && bf){
        uint u = *(const uint*)((const ushort*)xin + (long)(n0+1)*D + d0);
        xm[0] = __uint_as_float(u << 16);
        xm[1] = __uint_as_float(u & 0xffff0000u);
      } else {
        xm = *(const f32x2*)(xp32 + (long)(n0+1)*D + d0);
      }
      f32x2 hq;
      hq[0] = epsv*(xm[0] + vn2[0]) + accB[0];
      hq[1] = epsv*(xm[1] + vn2[1]) + accB[1];
      *(f32x2*)(hpre + (long)(n0+1)*D + d0) = hq;
    }
  }
}

// ---------------- fused node MLP: out = relu(h@W1+b1)@W2+b2 (MFMA hi/lo) ----------------
__global__ __launch_bounds__(256) void mlp_fused(
    const float* __restrict__ hpre,
    const ushort* __restrict__ w1hi, const ushort* __restrict__ w1lo,
    const ushort* __restrict__ w2hi, const ushort* __restrict__ w2lo,
    const void* __restrict__ b1v, const void* __restrict__ b2v, int layer,
    float* __restrict__ outp, int Nn, const int* __restrict__ flag)
{
  int bf = flag[0];
  __shared__ ushort sbuf[2][64][136];   // hi plane / lo plane; reused for packed h1
  __shared__ float bias1[D], bias2[D];
  int tid = threadIdx.x;
  if (tid < D){
    bias1[tid] = ldf(b1v, (long)layer*D + tid, bf);
    bias2[tid] = ldf(b2v, (long)layer*D + tid, bf);
  }
  // stage 64 rows of hpre -> LDS hi/lo (packed uint b32 writes)
  int srow = tid >> 2, scb = (tid & 3) << 5;
  long r = (long)blockIdx.x*64 + srow;
  {
    float hv[32];
    if (r < Nn){
      const float* xp = hpre + r*D + scb;
      #pragma unroll
      for (int j = 0; j < 32; j++) hv[j] = xp[j];
    } else {
      #pragma unroll
      for (int j = 0; j < 32; j++) hv[j] = 0.f;
    }
    uint* rowHi = (uint*)&sbuf[0][srow][0];
    uint* rowLo = (uint*)&sbuf[1][srow][0];
    #pragma unroll
    for (int j2 = 0; j2 < 16; j2++){
      float v0 = hv[2*j2], v1 = hv[2*j2+1];
      ushort h0 = f2bf(v0), h1 = f2bf(v1);
      ushort l0 = f2bf(v0 - bf2f(h0)), l1 = f2bf(v1 - bf2f(h1));
      rowHi[(scb>>1) + j2] = (uint)h0 | ((uint)h1 << 16);
      rowLo[(scb>>1) + j2] = (uint)l0 | ((uint)l1 << 16);
    }
  }
  __syncthreads();

  int lane = tid & 63, wvi = tid >> 6;
  int m = lane & 15, kq = lane >> 4;
  int lr = wvi*16 + m;
  short8 aHi[4], aLo[4];
  #pragma unroll
  for (int ki = 0; ki < 4; ki++){
    aHi[ki] = *(const short8*)&sbuf[0][lr][ki*32 + kq*8];
    aLo[ki] = *(const short8*)&sbuf[1][lr][ki*32 + kq*8];
  }
  // GEMM1 -> h1 (C layout), relu
  float h1[8][4];
  #pragma unroll
  for (int ci = 0; ci < 8; ci++){
    int c = ci*16 + m;
    f32x4 acc;
    float bv = bias1[c];
    acc[0] = bv; acc[1] = bv; acc[2] = bv; acc[3] = bv;
    const ushort* bp = w1hi + ((long)c << 7) + kq*8;
    #pragma unroll
    for (int ki = 0; ki < 4; ki++){
      short8 bfr = *(const short8*)(bp + ki*32);
      acc = __builtin_amdgcn_mfma_f32_16x16x32_bf16(aHi[ki], bfr, acc, 0, 0, 0);
      acc = __builtin_amdgcn_mfma_f32_16x16x32_bf16(aLo[ki], bfr, acc, 0, 0, 0);
    }
    if (!bf){
      const ushort* blp = w1lo + ((long)c << 7) + kq*8;
      #pragma unroll
      for (int ki = 0; ki < 4; ki++){
        short8 blr = *(const short8*)(blp + ki*32);
        acc = __builtin_amdgcn_mfma_f32_16x16x32_bf16(aHi[ki], blr, acc, 0, 0, 0);
      }
    }
    #pragma unroll
    for (int rg = 0; rg < 4; rg++) h1[ci][rg] = fmaxf(acc[rg], 0.f);
  }
  __syncthreads();   // all frag reads done; safe to reuse LDS
  // write h1 back packed (hi<<16 | lo), C-layout, b32 writes
  uint* h1p = (uint*)&sbuf[0][0][0];   // 64*132 uints fits in sbuf
  #pragma unroll
  for (int ci = 0; ci < 8; ci++){
    int c = ci*16 + m;
    #pragma unroll
    for (int rg = 0; rg < 4; rg++){
      int rl = wvi*16 + kq*4 + rg;
      float v = h1[ci][rg];
      ushort hi_ = f2bf(v);
      ushort lo_ = f2bf(v - bf2f(hi_));
      h1p[rl*132 + c] = ((uint)hi_ << 16) | (uint)lo_;
    }
  }
  __syncthreads();
  // rebuild A-frags for GEMM2 from packed h1
  #pragma unroll
  for (int ki = 0; ki < 4; ki++){
    const uint* up = h1p + lr*132 + ki*32 + kq*8;
    uint4 ua = *(const uint4*)up;
    uint4 ub = *(const uint4*)(up + 4);
    uint uu[8] = {ua.x,ua.y,ua.z,ua.w, ub.x,ub.y,ub.z,ub.w};
    short8 ah, al;
    #pragma unroll
    for (int t = 0; t < 8; t++){
      ah[t] = (short)(uu[t] >> 16);
      al[t] = (short)(uu[t] & 0xffffu);
    }
    aHi[ki] = ah; aLo[ki] = al;
  }
  long rowBase = (long)blockIdx.x*64 + wvi*16 + kq*4;
  #pragma unroll
  for (int ci = 0; ci < 8; ci++){
    int c = ci*16 + m;
    f32x4 acc;
    float bv = bias2[c];
    acc[0] = bv; acc[1] = bv; acc[2] = bv; acc[3] = bv;
    const ushort* bp = w2hi + ((long)c << 7) + kq*8;
    #pragma unroll
    for (int ki = 0; ki < 4; ki++){
      short8 bfr = *(const short8*)(bp + ki*32);
      acc = __builtin_amdgcn_mfma_f32_16x16x32_bf16(aHi[ki], bfr, acc, 0, 0, 0);
      acc = __builtin_amdgcn_mfma_f32_16x16x32_bf16(aLo[ki], bfr, acc, 0, 0, 0);
    }
    if (!bf){
      const ushort* blp = w2lo + ((long)c << 7) + kq*8;
      #pragma unroll
      for (int ki = 0; ki < 4; ki++){
        short8 blr = *(const short8*)(blp + ki*32);
        acc = __builtin_amdgcn_mfma_f32_16x16x32_bf16(aHi[ki], blr, acc, 0, 0, 0);
      }
    }
    #pragma unroll
    for (int rg = 0; rg < 4; rg++){
      long orow = rowBase + rg;
      if (orow < Nn) outp[orow*D + c] = acc[rg];
    }
  }
}

// ---------------- segment pool (batch is sorted) ----------------
__global__ __launch_bounds__(256) void pool_kernel(
    const float* __restrict__ x, const int* __restrict__ batch,
    int Nn, float* __restrict__ g, int colOff)
{
  __shared__ float part[128];
  int b = blockIdx.x;
  int c = threadIdx.x & 127, h = threadIdx.x >> 7;
  int lo = 0, hi = Nn;
  while (lo < hi){ int mid = (lo+hi)>>1; if (batch[mid] <  b) lo = mid+1; else hi = mid; }
  int start = lo;
  hi = Nn;
  while (lo < hi){ int mid = (lo+hi)>>1; if (batch[mid] <= b) lo = mid+1; else hi = mid; }
  int end = lo;
  float acc = 0.f;
  for (int r = start + h; r < end; r += 2) acc += x[(long)r*D + c];
  if (h) part[c] = acc;
  __syncthreads();
  if (!h) g[(long)b*384 + colOff + c] = acc + part[c];
}

// ---------------- head: Linear->LN->ReLU x2 -> Linear ----------------
__global__ __launch_bounds__(256) void head_kernel(
    const float* __restrict__ g,
    const void* __restrict__ w1, const void* __restrict__ b1,
    const void* __restrict__ g1, const void* __restrict__ be1,
    const void* __restrict__ w2, const void* __restrict__ b2,
    const void* __restrict__ g2, const void* __restrict__ be2,
    const void* __restrict__ ow, const void* __restrict__ ob,
    void* __restrict__ outp, const int* __restrict__ flag)
{
  int bf = flag[0];
  __shared__ float grow[384];
  __shared__ float h1[256];
  __shared__ float h2[128];
  __shared__ float redA[4], redB[4], stats[2];
  int b = blockIdx.x, tid = threadIdx.x;
  for (int i = tid; i < 384; i += 256) grow[i] = g[(long)b*384 + i];
  __syncthreads();
  float v = ldf(b1, tid, bf);
  for (int k = 0; k < 384; k++) v += grow[k] * ldf(w1, (long)k*256 + tid, bf);
  float s = v, s2 = v*v;
  for (int o = 32; o; o >>= 1){ s += __shfl_down(s,o); s2 += __shfl_down(s2,o); }
  if ((tid & 63) == 0){ redA[tid>>6] = s; redB[tid>>6] = s2; }
  __syncthreads();
  if (tid == 0){
    float S = redA[0]+redA[1]+redA[2]+redA[3];
    float S2 = redB[0]+redB[1]+redB[2]+redB[3];
    float mu = S / 256.f;
    stats[0] = mu; stats[1] = rsqrtf(S2/256.f - mu*mu + 1e-5f);
  }
  __syncthreads();
  float y = (v - stats[0]) * stats[1] * ldf(g1, tid, bf) + ldf(be1, tid, bf);
  h1[tid] = fmaxf(y, 0.f);
  __syncthreads();
  float v2 = 0.f;
  if (tid < 128){
    v2 = ldf(b2, tid, bf);
    for (int k = 0; k < 256; k++) v2 += h1[k] * ldf(w2, (long)k*128 + tid, bf);
  }
  float t = (tid < 128) ? v2 : 0.f;
  s = t; s2 = t*t;
  for (int o = 32; o; o >>= 1){ s += __shfl_down(s,o); s2 += __shfl_down(s2,o); }
  if ((tid & 63) == 0){ redA[tid>>6] = s; redB[tid>>6] = s2; }
  __syncthreads();
  if (tid == 0){
    float S = redA[0]+redA[1]+redA[2]+redA[3];
    float S2 = redB[0]+redB[1]+redB[2]+redB[3];
    float mu = S / 128.f;
    stats[0] = mu; stats[1] = rsqrtf(S2/128.f - mu*mu + 1e-5f);
  }
  __syncthreads();
  if (tid < 128){
    float y2 = (v2 - stats[0]) * stats[1] * ldf(g2, tid, bf) + ldf(be2, tid, bf);
    h2[tid] = fmaxf(y2, 0.f);
  }
  __syncthreads();
  float p = (tid < 128) ? h2[tid] * ldf(ow, tid, bf) : 0.f;
  s = p;
  for (int o = 32; o; o >>= 1) s += __shfl_down(s, o);
  if ((tid & 63) == 0) redA[tid>>6] = s;
  __syncthreads();
  if (tid == 0){
    float r = redA[0]+redA[1]+redA[2]+redA[3] + ldf(ob, 0, bf);
    if (bf) ((ushort*)outp)[b] = f2bf(r);
    else    ((float*)outp)[b]  = r;
  }
}

extern "C" void kernel_launch(void* const* d_in, const int* in_sizes, int n_in,
                              void* d_out, int out_size, void* d_ws, size_t ws_size,
                              hipStream_t stream)
{
  const void* x_in  = d_in[0];
  const int*  eidx  = (const int*)d_in[1];
  const void* eattr = d_in[2];
  const int*  batch = (const int*)d_in[3];
  const void* vn    = d_in[4];
  const void* ew    = d_in[5];
  const void* eb    = d_in[6];
  const void* epsp  = d_in[7];
  const void* w1p   = d_in[8];
  const void* b1p   = d_in[9];
  const void* w2p   = d_in[10];
  const void* b2p   = d_in[11];
  const void* lw1   = d_in[12];
  const void* lb1   = d_in[13];
  const void* ln1g  = d_in[14];
  const void* ln1b  = d_in[15];
  const void* lw2   = d_in[16];
  const void* lb2   = d_in[17];
  const void* ln2g  = d_in[18];
  const void* ln2b  = d_in[19];
  const void* owp   = d_in[20];
  const void* obp   = d_in[21];

  int Nn = in_sizes[0] / D;     // 50000
  int Ee = in_sizes[1] / 2;     // 600000
  int Gg = out_size;            // 512
  const int* srcp = eidx;
  const int* dstp = eidx + Ee;

  float*  A     = (float*)d_ws;                 // hpre scratch
  float*  B     = A + (size_t)Nn*D;             // layer outs (ping)
  float*  C     = B + (size_t)Nn*D;             // layer outs (pong)
  float*  gbuf  = C + (size_t)Nn*D;
  ushort* wT1hi = (ushort*)(gbuf + (size_t)Gg*384);
  ushort* wT1lo = wT1hi + 3*D*D;
  ushort* wT2hi = wT1lo + 3*D*D;
  ushort* wT2lo = wT2hi + 3*D*D;
  int*    flag  = (int*)(wT2lo + 3*D*D);
  int*    deg     = flag + 1;
  int*    rs      = deg + Nn;        // N+1
  int*    cursor  = rs + Nn + 1;
  int*    bsum    = cursor + Nn;
  int*    boff    = bsum + 256;
  int2*   spp     = (int2*)(boff + 256);

  detect_kernel<<<1,256,0,stream>>>((const uint*)x_in, flag);

  // CSR build (once; dst/src invariant across layers)
  int NB = (Nn + 511) / 512;
  hipMemsetAsync(deg, 0, (size_t)Nn*sizeof(int), stream);
  hist_kernel<<<(Ee+255)/256,256,0,stream>>>(dstp, deg, Ee);
  scan1_kernel<<<NB,256,0,stream>>>(deg, rs, bsum, Nn);
  scan2_kernel<<<1,256,0,stream>>>(bsum, boff, NB);
  scan3_kernel<<<(Nn+255)/256,256,0,stream>>>(rs, boff, cursor, Nn, Ee);
  scatter_kernel<<<(Ee+255)/256,256,0,stream>>>(dstp, srcp, cursor, spp, Ee);

  trans_kernel<<<192,256,0,stream>>>(w1p, wT1hi, wT1lo, flag);
  trans_kernel<<<192,256,0,stream>>>(w2p, wT2hi, wT2lo, flag);

  int mlpGrid = (Nn + 63) / 64;   // 782
  float* xcur = nullptr;
  for (int i = 0; i < 3; i++){
    float* out = (i == 1) ? C : B;    // L0->B, L1->C, L2->B
    if (i == 0)
      edge_agg_kernel<true ><<<2048,256,0,stream>>>(spp, rs, eattr, ew, eb, vn, epsp, i,
                                                    x_in, nullptr, A, Nn, flag);
    else
      edge_agg_kernel<false><<<2048,256,0,stream>>>(spp, rs, eattr, ew, eb, vn, epsp, i,
                                                    nullptr, xcur, A, Nn, flag);
    mlp_fused<<<mlpGrid,256,0,stream>>>(A,
                                        wT1hi + (size_t)i*D*D, wT1lo + (size_t)i*D*D,
                                        wT2hi + (size_t)i*D*D, wT2lo + (size_t)i*D*D,
                                        b1p, b2p, i, out, Nn, flag);
    pool_kernel<<<Gg,256,0,stream>>>(out, batch, Nn, gbuf, i*D);
    xcur = out;
  }
  head_kernel<<<Gg,256,0,stream>>>(gbuf, lw1, lb1, ln1g, ln1b,
                                   lw2, lb2, ln2g, ln2b, owp, obp, d_out, flag);
}